// Round 15
// baseline (196.174 us; speedup 1.0000x reference)
//
#include <hip/hip_runtime.h>

// Problem constants (z: [16, 64, 64, 64] f32, codebook: [2048, 64] f32)
#define C_DIM   64
#define HW      4096        // H*W
#define NROWS   65536       // B*H*W
#define N_E     2048
#define N_ELEM  4194304     // B*C*H*W
// Output layout (flat): z_q_out 4194304 | loss 1 | perplexity 1 | indices 65536
#define OUT_LOSS_OFF 4194304
#define OUT_PPL_OFF  4194305
#define OUT_IDX_OFF  4194306

#define ROWS_B   128                 // rows per block -> 512 blocks = 2/CU
#define NBLOCKS  (NROWS / ROWS_B)    // 512
#define NTILE    (N_E / 16)          // 128 code tiles of 16 codes
#define TILE_B   6144                // bytes per tile (6 frags x 64 lanes x 16B)

typedef __attribute__((ext_vector_type(8))) short bf16x8;
typedef __attribute__((ext_vector_type(4))) float f32x4;

// round-to-nearest-even f32 -> bf16 bits
__device__ __forceinline__ unsigned short f2bf(float f) {
    unsigned u = __float_as_uint(f);
    return (unsigned short)((u + 0x7FFFu + ((u >> 16) & 1u)) >> 16);
}
__device__ __forceinline__ float bf2f(unsigned short b) {
    return __uint_as_float(((unsigned)b) << 16);
}

// ---------------------------------------------------------------------------
// Prep (R10-proven, coalesced): one thread per (tile,k2,lane); fragment
// order unchanged since R4: elem off = ((tile*3+s)*2+k2)*512 + lane*8 + i.
// Zeroes counts/loss/ticket.
// ---------------------------------------------------------------------------
__global__ __launch_bounds__(256) void vq_prep(
    const float* __restrict__ cb, unsigned short* __restrict__ cbp,
    int* __restrict__ counts, float* __restrict__ loss_accum,
    int* __restrict__ done)
{
    const int u = blockIdx.x * 256 + threadIdx.x;   // [0, 16384)
    if (u < N_E) counts[u] = 0;
    if (u == 0)  { *loss_accum = 0.f; *done = 0; }

    const int lane = u & 63;
    const int k2   = (u >> 6) & 1;
    const int tile = u >> 7;                        // [0,128)
    const int c    = tile * 16 + (lane & 15);
    const int k0   = k2 * 32 + (lane >> 4) * 8;

    const float4 va = *(const float4*)(cb + (size_t)c * C_DIM + k0);
    const float4 vb = *(const float4*)(cb + (size_t)c * C_DIM + k0 + 4);
    const float v[8] = {va.x, va.y, va.z, va.w, vb.x, vb.y, vb.z, vb.w};

    bf16x8 s1v, s2v, s3v;
#pragma unroll
    for (int i = 0; i < 8; ++i) {                   // static indices only
        const unsigned short s1 = f2bf(v[i]);
        const float r1 = v[i] - bf2f(s1);
        const unsigned short s2 = f2bf(r1);
        const float r2 = r1 - bf2f(s2);
        s1v[i] = (short)s1;
        s2v[i] = (short)s2;
        s3v[i] = (short)f2bf(r2);
    }
    const size_t base = ((size_t)(tile * 3 + 0) * 2 + k2) * 512 + (size_t)lane * 8;
    *(bf16x8*)(cbp + base)        = s1v;            // s stride = 1024 elems
    *(bf16x8*)(cbp + base + 1024) = s2v;
    *(bf16x8*)(cbp + base + 2048) = s3v;
}

#define M16(A_, B_, C_) __builtin_amdgcn_mfma_f32_16x16x32_bf16((A_), (B_), (C_), 0, 0, 0)

// SIX split-passes (proven R14, absmax 0.0): (1,1)(1,2)(2,1)(2,2)(1,3)(3,1).
#define PASS6(AA, ACC, NT)                                                      \
    ACC = M16(AA[0], zf[0][NT][0], ACC); ACC = M16(AA[1], zf[0][NT][1], ACC);   \
    ACC = M16(AA[0], zf[1][NT][0], ACC); ACC = M16(AA[1], zf[1][NT][1], ACC);   \
    ACC = M16(AA[2], zf[0][NT][0], ACC); ACC = M16(AA[3], zf[0][NT][1], ACC);   \
    ACC = M16(AA[2], zf[1][NT][0], ACC); ACC = M16(AA[3], zf[1][NT][1], ACC);   \
    ACC = M16(AA[0], zf[2][NT][0], ACC); ACC = M16(AA[1], zf[2][NT][1], ACC);   \
    ACC = M16(AA[4], zf[0][NT][0], ACC); ACC = M16(AA[5], zf[0][NT][1], ACC);

// per-tile compute on A-register set AA: 24 MFMAs in 2 independent chains
#define COMPUTE_TILE(T_, AA)                                                    \
    {                                                                           \
        f32x4 acc0 = zero4, acc1 = zero4;                                       \
        PASS6(AA, acc0, 0)                                                      \
        PASS6(AA, acc1, 1)                                                      \
        const int cbase = (T_) * 16 + lg * 4;                                   \
        _Pragma("unroll")                                                       \
        for (int r = 0; r < 4; ++r) {                                           \
            if (acc0[r] > best0) { best0 = acc0[r]; bi0 = cbase + r; }          \
            if (acc1[r] > best1) { best1 = acc1[r]; bi1 = cbase + r; }          \
        }                                                                       \
    }

// async DMA staging of tile T_'s 6 KB into LDS buffer BUF (no VGPR round
// trip; cannot be sunk by the scheduler). 6 chunks of 1KB; wave w issues
// chunks w, w+4. Per instr: 64 lanes x 16B, per-lane global src, linear
// wave-uniform LDS dst (base + lane*16) — layout matches the ds_read side.
typedef const __attribute__((address_space(1))) unsigned int* gas_ptr;
typedef __attribute__((address_space(3))) unsigned int* las_ptr;
#define STAGE(BUF, T_)                                                          \
    for (int c = wv; c < 6; c += 4) {                                           \
        __builtin_amdgcn_global_load_lds(                                       \
            (gas_ptr)((const char*)cbp + (size_t)(T_) * TILE_B + c * 1024       \
                      + lane * 16),                                             \
            (las_ptr)((char*)&lbuf[BUF][0] + c * 1024), 16, 0, 0);              \
    }

// ---------------------------------------------------------------------------
// Main kernel (R15): R6/R14 loop shape (block = 128 rows, 4 waves; wave w
// owns rows [w*32,+32), scans all 2048 codes) with the A-stream moved from
// VGPR (compiler re-materialized loads at uses every round: VGPR stuck at
// 64 with zf=48 -> zero headroom -> ~560cyc/tile unhidden L2 latency) to
// double-buffered LDS via global_load_lds async DMA. Tile staged ONCE per
// block (4x less VMEM traffic); all 4 waves ds_read_b128 their frags
// (stride-16B, conflict-free). One __syncthreads per tile; its vmcnt drain
// waits on a transfer issued a full compute-phase earlier.
// ---------------------------------------------------------------------------
__global__ __launch_bounds__(256, 2) void vq_mfma(
    const float* __restrict__ z, const float* __restrict__ cb,
    const unsigned short* __restrict__ cbp, float* __restrict__ out,
    int* __restrict__ counts, float* __restrict__ loss_accum,
    int* __restrict__ done)
{
    __shared__ __align__(16) unsigned short lbuf[2][TILE_B / 2];  // 2 x 6 KB
    __shared__ int   sidx[ROWS_B];
    __shared__ float wsum[4];
    __shared__ int   slast;

    const int tid  = threadIdx.x;
    const int lane = tid & 63;
    const int wv   = tid >> 6;            // 0..3
    const int l15  = lane & 15, lg = lane >> 4;
    const int row0 = blockIdx.x * ROWS_B; // 128 rows, same b for whole block
    const int b    = row0 >> 12;
    const int hw0  = row0 & 4095;
    const float* zb = z + (size_t)b * C_DIM * HW + hw0;

    if (tid == 0) slast = 0;

    // ---- issue tile 0 staging immediately (lands under zf build) ----
    STAGE(0, 0)

    // ---- build z B-fragments straight from global (coalesced 64B runs) ----
    bf16x8 zf[3][2][2];
#pragma unroll
    for (int nt = 0; nt < 2; ++nt) {
        const int row_l = wv * 32 + nt * 16 + l15;
#pragma unroll
        for (int k2 = 0; k2 < 2; ++k2) {
#pragma unroll
            for (int i = 0; i < 8; ++i) {
                float v = zb[(size_t)(k2 * 32 + lg * 8 + i) * HW + row_l];
                unsigned short s1 = f2bf(v);
                float r1 = v - bf2f(s1);
                unsigned short s2 = f2bf(r1);
                float r2 = r1 - bf2f(s2);
                zf[0][nt][k2][i] = (short)s1;
                zf[1][nt][k2][i] = (short)s2;
                zf[2][nt][k2][i] = (short)f2bf(r2);
            }
        }
    }
    __syncthreads();                      // tile 0 staged (vmcnt drained)

    // ---- main loop: 128 tiles, LDS double-buffer, 1 barrier/tile ----
    float best0 = -3.4e38f, best1 = -3.4e38f;
    int   bi0 = 0, bi1 = 0;
    const f32x4 zero4 = {0.f, 0.f, 0.f, 0.f};

#pragma unroll 1
    for (int t = 0; t < NTILE; ++t) {
        if (t + 1 < NTILE) STAGE((t + 1) & 1, t + 1)   // async, pre-compute

        const bf16x8* Ab = (const bf16x8*)&lbuf[t & 1][0];
        bf16x8 A[6];
#pragma unroll
        for (int f = 0; f < 6; ++f) A[f] = Ab[f * 64 + lane];  // ds_read_b128

        COMPUTE_TILE(t, A)

        // barrier: (a) drains vmcnt -> tile t+1 staged; (b) all waves done
        // reading lbuf[t&1] before iter t+1 overwrites it with tile t+2.
        __syncthreads();
    }

    // ---- merge lane-groups (code sub-index) per chain via shfl ----
#pragma unroll
    for (int off = 16; off <= 32; off <<= 1) {
        float ob; int oi;
        ob = __shfl_xor(best0, off, 64); oi = __shfl_xor(bi0, off, 64);
        if (ob > best0 || (ob == best0 && oi < bi0)) { best0 = ob; bi0 = oi; }
        ob = __shfl_xor(best1, off, 64); oi = __shfl_xor(bi1, off, 64);
        if (ob > best1 || (ob == best1 && oi < bi1)) { best1 = ob; bi1 = oi; }
    }
    if (lane < 32) {
        const int nt = lane >> 4;
        const int row_l = wv * 32 + lane;          // = wv*32 + nt*16 + l15
        const int ii = (nt == 0) ? bi0 : bi1;
        sidx[row_l] = ii;
        out[OUT_IDX_OFF + row0 + row_l] = (float)ii;
        atomicAdd(&counts[ii], 1);
    }
    __syncthreads();

    // ---- fused epilogue: gather cb[idx], ST-write, loss partial ----
    float* ob0 = out + (size_t)b * C_DIM * HW + hw0;
    float lsum = 0.f;
#pragma unroll
    for (int j = 0; j < 8; ++j) {
        const int m = j * 256 + tid;               // [0,2048) float4 units
        const int r = m & 127, c4 = m >> 7;
        const float4 q4 = *(const float4*)(cb + (size_t)sidx[r] * C_DIM + c4 * 4);
#pragma unroll
        for (int q = 0; q < 4; ++q) {
            const int c = c4 * 4 + q;
            const float zv = zb[(size_t)c * HW + r];
            const float qv = (q == 0) ? q4.x : (q == 1) ? q4.y : (q == 2) ? q4.z : q4.w;
            const float d = qv - zv;               // same fp order as reference ST
            lsum += d * d;
            ob0[(size_t)c * HW + r] = zv + d;
        }
    }
    for (int off = 32; off > 0; off >>= 1) lsum += __shfl_down(lsum, off, 64);
    if (lane == 0) wsum[wv] = lsum;
    __syncthreads();

    // ---- last-block inline finalize (proven R8) ----
    if (tid == 0) {
        atomicAdd(loss_accum, wsum[0] + wsum[1] + wsum[2] + wsum[3]);
        __threadfence();                            // publish counts + loss
        const int tk = atomicAdd(done, 1);
        if (tk == NBLOCKS - 1) slast = 1;
    }
    __syncthreads();
    if (slast) {
        __threadfence();                            // acquire side
        float h = 0.f;
        for (int e = tid; e < N_E; e += 256) {
            const int cnt = atomicAdd(&counts[e], 0);   // device-scope read
            const float em = (float)cnt * (1.0f / (float)NROWS);
            h -= em * logf(em + 1e-10f);
        }
        for (int off = 32; off > 0; off >>= 1) h += __shfl_down(h, off, 64);
        if (lane == 0) wsum[wv] = h;
        __syncthreads();
        if (tid == 0) {
            const float H = wsum[0] + wsum[1] + wsum[2] + wsum[3];
            const float L = atomicAdd(loss_accum, 0.f); // device-scope read
            const float m = L * (1.0f / (float)N_ELEM);
            out[OUT_LOSS_OFF] = 0.25f * m + m;   // BETA*mean + mean
            out[OUT_PPL_OFF]  = expf(H);
        }
    }
}

extern "C" void kernel_launch(void* const* d_in, const int* in_sizes, int n_in,
                              void* d_out, int out_size, void* d_ws, size_t ws_size,
                              hipStream_t stream)
{
    const float* z  = (const float*)d_in[0];
    const float* cb = (const float*)d_in[1];
    float* out = (float*)d_out;

    // ws: counts[2048] int | loss f32 | done int | pad | cbp bf16 (768KB) @16KB
    int*            counts     = (int*)d_ws;
    float*          loss_accum = (float*)((char*)d_ws + N_E * sizeof(int));
    int*            done       = (int*)((char*)d_ws + N_E * sizeof(int) + 4);
    unsigned short* cbp        = (unsigned short*)((char*)d_ws + 16384);

    vq_prep<<<64, 256, 0, stream>>>(cb, cbp, counts, loss_accum, done);
    vq_mfma<<<NBLOCKS, 256, 0, stream>>>(z, cb, cbp, out, counts, loss_accum, done);
}

// Round 18
// 167.368 us; speedup vs baseline: 1.1721x; 1.1721x over previous
//
#include <hip/hip_runtime.h>

// Problem constants (z: [16, 64, 64, 64] f32, codebook: [2048, 64] f32)
#define C_DIM   64
#define HW      4096        // H*W
#define NROWS   65536       // B*H*W
#define N_E     2048
#define N_ELEM  4194304     // B*C*H*W
// Output layout (flat): z_q_out 4194304 | loss 1 | perplexity 1 | indices 65536
#define OUT_LOSS_OFF 4194304
#define OUT_PPL_OFF  4194305
#define OUT_IDX_OFF  4194306

#define ROWS_B   128                 // rows per block -> 512 blocks = 2/CU
#define NBLOCKS  (NROWS / ROWS_B)    // 512
#define NTILE    (N_E / 16)          // 128 code tiles of 16 codes
#define TILE_U   384                 // 16B units per tile (6 frags x 64 lanes)

typedef __attribute__((ext_vector_type(8))) short bf16x8;
typedef __attribute__((ext_vector_type(4))) float f32x4;

// round-to-nearest-even f32 -> bf16 bits
__device__ __forceinline__ unsigned short f2bf(float f) {
    unsigned u = __float_as_uint(f);
    return (unsigned short)((u + 0x7FFFu + ((u >> 16) & 1u)) >> 16);
}
__device__ __forceinline__ float bf2f(unsigned short b) {
    return __uint_as_float(((unsigned)b) << 16);
}

// ---------------------------------------------------------------------------
// Prep (R10-proven, coalesced): one thread per (tile,k2,lane); fragment
// order unchanged since R4: elem off = ((tile*3+s)*2+k2)*512 + lane*8 + i.
// Zeroes counts/loss/ticket.
// ---------------------------------------------------------------------------
__global__ __launch_bounds__(256) void vq_prep(
    const float* __restrict__ cb, unsigned short* __restrict__ cbp,
    int* __restrict__ counts, float* __restrict__ loss_accum,
    int* __restrict__ done)
{
    const int u = blockIdx.x * 256 + threadIdx.x;   // [0, 16384)
    if (u < N_E) counts[u] = 0;
    if (u == 0)  { *loss_accum = 0.f; *done = 0; }

    const int lane = u & 63;
    const int k2   = (u >> 6) & 1;
    const int tile = u >> 7;                        // [0,128)
    const int c    = tile * 16 + (lane & 15);
    const int k0   = k2 * 32 + (lane >> 4) * 8;

    const float4 va = *(const float4*)(cb + (size_t)c * C_DIM + k0);
    const float4 vb = *(const float4*)(cb + (size_t)c * C_DIM + k0 + 4);
    const float v[8] = {va.x, va.y, va.z, va.w, vb.x, vb.y, vb.z, vb.w};

    bf16x8 s1v, s2v, s3v;
#pragma unroll
    for (int i = 0; i < 8; ++i) {                   // static indices only
        const unsigned short s1 = f2bf(v[i]);
        const float r1 = v[i] - bf2f(s1);
        const unsigned short s2 = f2bf(r1);
        const float r2 = r1 - bf2f(s2);
        s1v[i] = (short)s1;
        s2v[i] = (short)s2;
        s3v[i] = (short)f2bf(r2);
    }
    const size_t base = ((size_t)(tile * 3 + 0) * 2 + k2) * 512 + (size_t)lane * 8;
    *(bf16x8*)(cbp + base)        = s1v;            // s stride = 1024 elems
    *(bf16x8*)(cbp + base + 1024) = s2v;
    *(bf16x8*)(cbp + base + 2048) = s3v;
}

#define M16(A_, B_, C_) __builtin_amdgcn_mfma_f32_16x16x32_bf16((A_), (B_), (C_), 0, 0, 0)

// SIX split-passes (proven R14, absmax 0.0): (1,1)(1,2)(2,1)(2,2)(1,3)(3,1).
#define PASS6(AA, ACC, NT)                                                      \
    ACC = M16(AA[0], zf[0][NT][0], ACC); ACC = M16(AA[1], zf[0][NT][1], ACC);   \
    ACC = M16(AA[0], zf[1][NT][0], ACC); ACC = M16(AA[1], zf[1][NT][1], ACC);   \
    ACC = M16(AA[2], zf[0][NT][0], ACC); ACC = M16(AA[3], zf[0][NT][1], ACC);   \
    ACC = M16(AA[2], zf[1][NT][0], ACC); ACC = M16(AA[3], zf[1][NT][1], ACC);   \
    ACC = M16(AA[0], zf[2][NT][0], ACC); ACC = M16(AA[1], zf[2][NT][1], ACC);   \
    ACC = M16(AA[4], zf[0][NT][0], ACC); ACC = M16(AA[5], zf[0][NT][1], ACC);

// per-tile compute on A-register set AA: 24 MFMAs in 2 independent chains.
// R18: s_setprio(1) around the cluster (T5) — with no loop barriers the two
// resident waves/SIMD free-run; priority on the MFMA phase pushes them into
// antiphase so one wave's vmcnt stall hides under the other's compute.
// Pure scheduler hint: no ordering/memory semantics, results unchanged.
#define COMPUTE_TILE(T_, AA)                                                    \
    {                                                                           \
        f32x4 acc0 = zero4, acc1 = zero4;                                       \
        __builtin_amdgcn_s_setprio(1);                                          \
        PASS6(AA, acc0, 0)                                                      \
        PASS6(AA, acc1, 1)                                                      \
        __builtin_amdgcn_s_setprio(0);                                          \
        const int cbase = (T_) * 16 + lg * 4;                                   \
        _Pragma("unroll")                                                       \
        for (int r = 0; r < 4; ++r) {                                           \
            if (acc0[r] > best0) { best0 = acc0[r]; bi0 = cbase + r; }          \
            if (acc1[r] > best1) { best1 = acc1[r]; bi1 = cbase + r; }          \
        }                                                                       \
    }

// load A-frag set for tile T_ (6 x global_load_dwordx4, coalesced)
#define LOADA(AA, T_)                                                           \
    {                                                                           \
        const bf16x8* p_ = cbpf + (size_t)(T_) * TILE_U;                        \
        _Pragma("unroll")                                                       \
        for (int f = 0; f < 6; ++f) AA[f] = p_[f * 64 + lane];                  \
    }

// ---------------------------------------------------------------------------
// Main kernel: R14 structure verbatim (block = 128 rows, 4 waves; wave w
// owns rows [w*32,+32), scans all 2048 codes; PASS6; compiler-scheduled
// 2-deep ping-pong; no fences, no loop barriers) + setprio. Last-finishing
// block finalizes loss/ppl inline (proven R8).
// ---------------------------------------------------------------------------
__global__ __launch_bounds__(256, 2) void vq_mfma(
    const float* __restrict__ z, const float* __restrict__ cb,
    const unsigned short* __restrict__ cbp, float* __restrict__ out,
    int* __restrict__ counts, float* __restrict__ loss_accum,
    int* __restrict__ done)
{
    __shared__ int   sidx[ROWS_B];
    __shared__ float wsum[4];
    __shared__ int   slast;

    const int tid  = threadIdx.x;
    const int lane = tid & 63;
    const int wv   = tid >> 6;            // 0..3
    const int l15  = lane & 15, lg = lane >> 4;
    const int row0 = blockIdx.x * ROWS_B; // 128 rows, same b for whole block
    const int b    = row0 >> 12;
    const int hw0  = row0 & 4095;
    const float* zb = z + (size_t)b * C_DIM * HW + hw0;

    if (tid == 0) slast = 0;

    // ---- build z B-fragments straight from global (coalesced 64B runs) ----
    bf16x8 zf[3][2][2];
#pragma unroll
    for (int nt = 0; nt < 2; ++nt) {
        const int row_l = wv * 32 + nt * 16 + l15;
#pragma unroll
        for (int k2 = 0; k2 < 2; ++k2) {
#pragma unroll
            for (int i = 0; i < 8; ++i) {
                float v = zb[(size_t)(k2 * 32 + lg * 8 + i) * HW + row_l];
                unsigned short s1 = f2bf(v);
                float r1 = v - bf2f(s1);
                unsigned short s2 = f2bf(r1);
                float r2 = r1 - bf2f(s2);
                zf[0][nt][k2][i] = (short)s1;
                zf[1][nt][k2][i] = (short)s2;
                zf[2][nt][k2][i] = (short)f2bf(r2);
            }
        }
    }

    // ---- main loop: 128 tiles, 2-deep ping-pong, no barriers ----
    const bf16x8* cbpf = (const bf16x8*)cbp;
    float best0 = -3.4e38f, best1 = -3.4e38f;
    int   bi0 = 0, bi1 = 0;
    const f32x4 zero4 = {0.f, 0.f, 0.f, 0.f};

    bf16x8 Acur[6], Anxt[6];
    LOADA(Acur, 0)

#pragma unroll 1
    for (int t = 0; t < NTILE; t += 2) {
        LOADA(Anxt, t + 1)               // in flight under tile t's compute
        COMPUTE_TILE(t, Acur)
        if (t + 2 < NTILE) LOADA(Acur, t + 2)
        COMPUTE_TILE(t + 1, Anxt)
    }

    // ---- merge lane-groups (code sub-index) per chain via shfl ----
#pragma unroll
    for (int off = 16; off <= 32; off <<= 1) {
        float ob; int oi;
        ob = __shfl_xor(best0, off, 64); oi = __shfl_xor(bi0, off, 64);
        if (ob > best0 || (ob == best0 && oi < bi0)) { best0 = ob; bi0 = oi; }
        ob = __shfl_xor(best1, off, 64); oi = __shfl_xor(bi1, off, 64);
        if (ob > best1 || (ob == best1 && oi < bi1)) { best1 = ob; bi1 = oi; }
    }
    if (lane < 32) {
        const int nt = lane >> 4;
        const int row_l = wv * 32 + lane;          // = wv*32 + nt*16 + l15
        const int ii = (nt == 0) ? bi0 : bi1;
        sidx[row_l] = ii;
        out[OUT_IDX_OFF + row0 + row_l] = (float)ii;
        atomicAdd(&counts[ii], 1);
    }
    __syncthreads();

    // ---- fused epilogue: gather cb[idx], ST-write, loss partial ----
    float* ob0 = out + (size_t)b * C_DIM * HW + hw0;
    float lsum = 0.f;
#pragma unroll
    for (int j = 0; j < 8; ++j) {
        const int m = j * 256 + tid;               // [0,2048) float4 units
        const int r = m & 127, c4 = m >> 7;
        const float4 q4 = *(const float4*)(cb + (size_t)sidx[r] * C_DIM + c4 * 4);
#pragma unroll
        for (int q = 0; q < 4; ++q) {
            const int c = c4 * 4 + q;
            const float zv = zb[(size_t)c * HW + r];
            const float qv = (q == 0) ? q4.x : (q == 1) ? q4.y : (q == 2) ? q4.z : q4.w;
            const float d = qv - zv;               // same fp order as reference ST
            lsum += d * d;
            ob0[(size_t)c * HW + r] = zv + d;
        }
    }
    for (int off = 32; off > 0; off >>= 1) lsum += __shfl_down(lsum, off, 64);
    if (lane == 0) wsum[wv] = lsum;
    __syncthreads();

    // ---- last-block inline finalize (proven R8) ----
    if (tid == 0) {
        atomicAdd(loss_accum, wsum[0] + wsum[1] + wsum[2] + wsum[3]);
        __threadfence();                            // publish counts + loss
        const int tk = atomicAdd(done, 1);
        if (tk == NBLOCKS - 1) slast = 1;
    }
    __syncthreads();
    if (slast) {
        __threadfence();                            // acquire side
        float h = 0.f;
        for (int e = tid; e < N_E; e += 256) {
            const int cnt = atomicAdd(&counts[e], 0);   // device-scope read
            const float em = (float)cnt * (1.0f / (float)NROWS);
            h -= em * logf(em + 1e-10f);
        }
        for (int off = 32; off > 0; off >>= 1) h += __shfl_down(h, off, 64);
        if (lane == 0) wsum[wv] = h;
        __syncthreads();
        if (tid == 0) {
            const float H = wsum[0] + wsum[1] + wsum[2] + wsum[3];
            const float L = atomicAdd(loss_accum, 0.f); // device-scope read
            const float m = L * (1.0f / (float)N_ELEM);
            out[OUT_LOSS_OFF] = 0.25f * m + m;   // BETA*mean + mean
            out[OUT_PPL_OFF]  = expf(H);
        }
    }
}

extern "C" void kernel_launch(void* const* d_in, const int* in_sizes, int n_in,
                              void* d_out, int out_size, void* d_ws, size_t ws_size,
                              hipStream_t stream)
{
    const float* z  = (const float*)d_in[0];
    const float* cb = (const float*)d_in[1];
    float* out = (float*)d_out;

    // ws: counts[2048] int | loss f32 | done int | pad | cbp bf16 (768KB) @16KB
    int*            counts     = (int*)d_ws;
    float*          loss_accum = (float*)((char*)d_ws + N_E * sizeof(int));
    int*            done       = (int*)((char*)d_ws + N_E * sizeof(int) + 4);
    unsigned short* cbp        = (unsigned short*)((char*)d_ws + 16384);

    vq_prep<<<64, 256, 0, stream>>>(cb, cbp, counts, loss_accum, done);
    vq_mfma<<<NBLOCKS, 256, 0, stream>>>(z, cb, cbp, out, counts, loss_accum, done);
}